// Round 9
// baseline (160.259 us; speedup 1.0000x reference)
//
#include <hip/hip_runtime.h>
#include <hip/hip_fp16.h>
#include <cmath>
#include <cstdint>

#define NLOD 10

// Codebook sizes are certain at compile time: min(lod^2, 1024).
static constexpr int SIZES[NLOD]     = {49, 64, 121, 196, 324, 529, 900, 1024, 1024, 1024};
static constexpr int ENTRY_OFS[NLOD] = {0, 49, 113, 234, 430, 754, 1283, 2183, 3207, 4231};
// Levels 0..5 live in LDS (1283 entries * 8 B = 10264 B); levels 6..9 are
// gathered from d_ws (f16x4-packed, 31.8 KB, L1/L2-resident) on the VMEM pipe.
static constexpr int LDS_ENTRIES = 1283;
// ws entry offsets for levels 6..9 (entries, 8 B each, contiguous)
static constexpr int WS_OFS[4] = {0, 900, 1924, 2948};   // 6,7,8,9
static constexpr int WS_ENTRIES = 3972;

struct ResArr { int r[NLOD]; };

// ---- shared per-level math (hash terms + factorized weights) ----
struct LevelCtx {
    unsigned h00, h01, h10, h11, hz0, hz1;
    float w00z0, w00z1, w01z0, w01z1, w10z0, w10z1, w11z0, w11z1;
};

template <int SIZE>
__device__ __forceinline__ LevelCtx level_ctx(int res, float px, float py, float pz)
{
    constexpr bool POW2 = (SIZE & (SIZE - 1)) == 0;
    constexpr unsigned P1 = 2654435761u, P2 = 805459861u;

    const float s = (float)(res - 1);
    float fx = px * s, fy = py * s, fz = pz * s;

    // clip(floor(x),0,res-2) == floor(x) exactly for px in [0,1) (R5 proof).
    float gx = floorf(fx), gy = floorf(fy), gz = floorf(fz);
    float wx = fx - gx, wy = fy - gy, wz = fz - gz;

    unsigned ux = (unsigned)(int)gx;
    unsigned uy = (unsigned)(int)gy;
    unsigned uz = (unsigned)(int)gz;

    LevelCtx c;
    unsigned hx0, hx1, hy0, hy1;
    if constexpr (POW2) {   // fold the *8 byte-scale into the hash components
        hx0 = ux << 3;        hx1 = hx0 + 8u;
        hy0 = uy * (P1 * 8u); hy1 = hy0 + (P1 * 8u);
        c.hz0 = uz * (P2 * 8u); c.hz1 = c.hz0 + (P2 * 8u);
    } else {
        hx0 = ux;       hx1 = ux + 1u;
        hy0 = uy * P1;  hy1 = hy0 + P1;
        c.hz0 = uz * P2; c.hz1 = c.hz0 + P2;
    }
    c.h00 = hx0 ^ hy0; c.h01 = hx0 ^ hy1;
    c.h10 = hx1 ^ hy0; c.h11 = hx1 ^ hy1;

    float wx0 = 1.0f - wx, wy0 = 1.0f - wy, wz0 = 1.0f - wz;
    float w00 = wx0 * wy0, w01 = wx0 * wy, w10 = wx * wy0, w11 = wx * wy;
    c.w00z0 = w00 * wz0; c.w00z1 = w00 * wz;
    c.w01z0 = w01 * wz0; c.w01z1 = w01 * wz;
    c.w10z0 = w10 * wz0; c.w10z1 = w10 * wz;
    c.w11z0 = w11 * wz0; c.w11z1 = w11 * wz;
    return c;
}

// fma_mix accumulate: consumes the b64 payload's f16 halves in place via
// op_sel. Numerically identical to fpext+fused-fma. (R2-R5 proven codegen.)
__device__ __forceinline__ void acc3(uint2 raw, float wt,
                                     float& a0, float& a1, float& a2)
{
    asm("v_fma_mix_f32 %0, %1, %2, %0 op_sel_hi:[1,0,0]"
        : "+v"(a0) : "v"(raw.x), "v"(wt));
    asm("v_fma_mix_f32 %0, %1, %2, %0 op_sel:[1,0,0] op_sel_hi:[1,0,0]"
        : "+v"(a1) : "v"(raw.x), "v"(wt));
    asm("v_fma_mix_f32 %0, %1, %2, %0 op_sel_hi:[1,0,0]"
        : "+v"(a2) : "v"(raw.y), "v"(wt));
}

// LDS level (one ds_read_b64 per corner)
template <int SIZE>
__device__ __forceinline__ void level_lds(const __half* __restrict__ cb, int res,
                                          float px, float py, float pz,
                                          float& a0, float& a1, float& a2)
{
    constexpr bool POW2 = (SIZE & (SIZE - 1)) == 0;
    LevelCtx c = level_ctx<SIZE>(res, px, py, pz);

    auto corner = [&](unsigned h, float wt) {
        uint2 raw;
        if constexpr (POW2) {
            unsigned addr = h & (unsigned)((SIZE - 1) * 8);
            raw = *reinterpret_cast<const uint2*>(reinterpret_cast<const char*>(cb) + addr);
        } else {
            unsigned idx = h % (unsigned)SIZE;   // constexpr divisor -> magic mul
            raw = reinterpret_cast<const uint2*>(cb)[idx];
        }
        acc3(raw, wt, a0, a1, a2);
    };

    corner(c.h00 ^ c.hz0, c.w00z0);
    corner(c.h00 ^ c.hz1, c.w00z1);
    corner(c.h01 ^ c.hz0, c.w01z0);
    corner(c.h01 ^ c.hz1, c.w01z1);
    corner(c.h10 ^ c.hz0, c.w10z0);
    corner(c.h10 ^ c.hz1, c.w10z1);
    corner(c.h11 ^ c.hz0, c.w11z0);
    corner(c.h11 ^ c.hz1, c.w11z1);
}

// Global-memory level: one global_load_dwordx2 per corner, served from L1/L2
// (tables total 31.8 KB). Moves gather work off the LDS pipe onto VMEM.
template <int SIZE>
__device__ __forceinline__ void level_g(const char* __restrict__ cb, int res,
                                        float px, float py, float pz,
                                        float& a0, float& a1, float& a2)
{
    constexpr bool POW2 = (SIZE & (SIZE - 1)) == 0;
    LevelCtx c = level_ctx<SIZE>(res, px, py, pz);

    auto corner = [&](unsigned h, float wt) {
        unsigned addr;
        if constexpr (POW2) {
            addr = h & (unsigned)((SIZE - 1) * 8);
        } else {
            addr = (h % (unsigned)SIZE) * 8u;
        }
        uint2 raw = *reinterpret_cast<const uint2*>(cb + addr);
        acc3(raw, wt, a0, a1, a2);
    };

    corner(c.h00 ^ c.hz0, c.w00z0);
    corner(c.h00 ^ c.hz1, c.w00z1);
    corner(c.h01 ^ c.hz0, c.w01z0);
    corner(c.h01 ^ c.hz1, c.w01z1);
    corner(c.h10 ^ c.hz0, c.w10z0);
    corner(c.h10 ^ c.hz1, c.w10z1);
    corner(c.h11 ^ c.hz0, c.w11z0);
    corner(c.h11 ^ c.hz1, c.w11z1);
}

// Pre-kernel: pack codebooks 6..9 (f32x3) -> f16x4 contiguously into d_ws.
// Runs every launch (d_ws re-poisoned before each timed call).
__global__ void pack_kernel(const float* __restrict__ c6, const float* __restrict__ c7,
                            const float* __restrict__ c8, const float* __restrict__ c9,
                            __half2* __restrict__ ws)
{
    int t = blockIdx.x * blockDim.x + threadIdx.x;   // 0..4095
    if (t >= WS_ENTRIES) return;
    const float* src;
    if      (t < 900)  src = c6 + t * 3;
    else if (t < 1924) src = c7 + (t - 900) * 3;
    else if (t < 2948) src = c8 + (t - 1924) * 3;
    else               src = c9 + (t - 2948) * 3;
    ws[t * 2 + 0] = __floats2half2_rn(src[0], src[1]);
    ws[t * 2 + 1] = __floats2half2_rn(src[2], 0.0f);
}

__global__ __launch_bounds__(1024, 8)
void hashgrid_kernel(const float* __restrict__ pts,
                     const float* __restrict__ c0, const float* __restrict__ c1,
                     const float* __restrict__ c2, const float* __restrict__ c3,
                     const float* __restrict__ c4, const float* __restrict__ c5,
                     const char* __restrict__ gws,
                     float* __restrict__ out, int npts, ResArr res)
{
    __shared__ __half cbh[LDS_ENTRIES * 4];   // 10264 B, levels 0..5

    {
        const float* srcs[6] = {c0, c1, c2, c3, c4, c5};
#pragma unroll
        for (int L = 0; L < 6; ++L) {
            for (int e = threadIdx.x; e < SIZES[L]; e += blockDim.x) {
                const float* s = srcs[L] + e * 3;
                __half2* d = reinterpret_cast<__half2*>(cbh + (ENTRY_OFS[L] + e) * 4);
                d[0] = __floats2half2_rn(s[0], s[1]);
                d[1] = __floats2half2_rn(s[2], 0.0f);
            }
        }
    }
    __syncthreads();

    const char* g6 = gws + WS_OFS[0] * 8;
    const char* g7 = gws + WS_OFS[1] * 8;
    const char* g8 = gws + WS_OFS[2] * 8;
    const char* g9 = gws + WS_OFS[3] * 8;

    // Two points per thread per iteration (16 independent gathers in flight).
    const int S = gridDim.x * blockDim.x;
    for (int n = blockIdx.x * blockDim.x + threadIdx.x; n < npts; n += 2 * S) {
        const int m = n + S;
        const bool hasB = (m < npts);
        const int mc = hasB ? m : n;

        float ax = pts[n * 3 + 0], ay = pts[n * 3 + 1], az = pts[n * 3 + 2];
        float bx = pts[mc * 3 + 0], by = pts[mc * 3 + 1], bz = pts[mc * 3 + 2];

        float A0 = 0.0f, A1 = 0.0f, A2 = 0.0f;
        float B0 = 0.0f, B1 = 0.0f, B2 = 0.0f;

#define LEVEL2(SZ, L)                                                             \
        level_lds<SZ>(cbh + ENTRY_OFS[L] * 4, res.r[L], ax, ay, az, A0, A1, A2);  \
        level_lds<SZ>(cbh + ENTRY_OFS[L] * 4, res.r[L], bx, by, bz, B0, B1, B2);

        LEVEL2(  49, 0)
        LEVEL2(  64, 1)
        LEVEL2( 121, 2)
        LEVEL2( 196, 3)
        LEVEL2( 324, 4)
        LEVEL2( 529, 5)
#undef LEVEL2
        // Levels 6..9 from global (VMEM pipe; 31.8 KB of L1/L2-resident tables)
        level_g< 900>(g6, res.r[6], ax, ay, az, A0, A1, A2);
        level_g< 900>(g6, res.r[6], bx, by, bz, B0, B1, B2);
        level_g<1024>(g7, res.r[7], ax, ay, az, A0, A1, A2);
        level_g<1024>(g7, res.r[7], bx, by, bz, B0, B1, B2);
        level_g<1024>(g8, res.r[8], ax, ay, az, A0, A1, A2);
        level_g<1024>(g8, res.r[8], bx, by, bz, B0, B1, B2);
        level_g<1024>(g9, res.r[9], ax, ay, az, A0, A1, A2);
        level_g<1024>(g9, res.r[9], bx, by, bz, B0, B1, B2);

        out[n * 3 + 0] = A0;
        out[n * 3 + 1] = A1;
        out[n * 3 + 2] = A2;
        if (hasB) {
            out[m * 3 + 0] = B0;
            out[m * 3 + 1] = B1;
            out[m * 3 + 2] = B2;
        }
    }
}

extern "C" void kernel_launch(void* const* d_in, const int* in_sizes, int n_in,
                              void* d_out, int out_size, void* d_ws, size_t ws_size,
                              hipStream_t stream)
{
    const float* pts = (const float*)d_in[0];
    const int npts = in_sizes[0] / 3;

    // Replicate numpy's exact double-precision LOD computation (glibc libm):
    // LOD 9 sits at 6*b^9 == 64.0 +/- ~1e-14, floor() is boundary-sensitive.
    ResArr ra;
    const double b = exp((log(64.0) - log(6.0)) / 9.0);
    for (int l = 0; l < NLOD; ++l)
        ra.r[l] = (int)(1.0 + floor(6.0 * pow(b, (double)l)));

    // Pack levels 6..9 into d_ws as f16x4 (31.8 KB; rewritten every call).
    pack_kernel<<<dim3(16), dim3(256), 0, stream>>>(
        (const float*)d_in[7], (const float*)d_in[8],
        (const float*)d_in[9], (const float*)d_in[10], (__half2*)d_ws);

    // 512 blocks x 1024 thr: 2 blocks/CU (wave cap 32/CU), 10.3 KB LDS each.
    hashgrid_kernel<<<dim3(512), dim3(1024), 0, stream>>>(
        pts,
        (const float*)d_in[1], (const float*)d_in[2], (const float*)d_in[3],
        (const float*)d_in[4], (const float*)d_in[5], (const float*)d_in[6],
        (const char*)d_ws,
        (float*)d_out, npts, ra);
}

// Round 10
// 148.325 us; speedup vs baseline: 1.0805x; 1.0805x over previous
//
#include <hip/hip_runtime.h>
#include <hip/hip_fp16.h>
#include <cmath>
#include <cstdint>

#define NLOD 10

// Codebook sizes are certain at compile time: min(lod^2, 1024).
static constexpr int SIZES[NLOD]     = {49, 64, 121, 196, 324, 529, 900, 1024, 1024, 1024};
static constexpr int ENTRY_OFS[NLOD] = {0, 49, 113, 234, 430, 754, 1283, 2183, 3207, 4231};
// Levels 0..7 in LDS (3207 entries * 8 B = 25656 B); levels 8,9 gathered from
// d_ws (f16x4, 8 KB each, L1-resident) on the VMEM pipe.  (R8's best split.)
static constexpr int LDS_ENTRIES = 3207;

struct ResArr { int r[NLOD]; };

// fma_mix accumulate: consumes the b64 payload's f16 halves in place via
// op_sel. Numerically identical to fpext+fused-fma. (R2-R8 proven codegen.)
__device__ __forceinline__ void acc3(uint2 raw, float wt,
                                     float& a0, float& a1, float& a2)
{
    asm("v_fma_mix_f32 %0, %1, %2, %0 op_sel_hi:[1,0,0]"
        : "+v"(a0) : "v"(raw.x), "v"(wt));
    asm("v_fma_mix_f32 %0, %1, %2, %0 op_sel:[1,0,0] op_sel_hi:[1,0,0]"
        : "+v"(a1) : "v"(raw.x), "v"(wt));
    asm("v_fma_mix_f32 %0, %1, %2, %0 op_sel_hi:[1,0,0]"
        : "+v"(a2) : "v"(raw.y), "v"(wt));
}

// Issue a level's 8 gathers into named regs + stash the 8 corner weights.
// GLOBAL=false: ds_read_b64 from LDS.  GLOBAL=true: global_load_dwordx2.
template <int SIZE, bool GLOBAL>
__device__ __forceinline__ void load_level(const char* __restrict__ cb, int res,
                                           float px, float py, float pz,
                                           uint2 (&r)[8], float (&w)[8])
{
    constexpr bool POW2 = (SIZE & (SIZE - 1)) == 0;
    constexpr unsigned P1 = 2654435761u, P2 = 805459861u;

    const float s = (float)(res - 1);
    float fx = px * s, fy = py * s, fz = pz * s;

    // clip(floor(x),0,res-2) == floor(x) exactly for px in [0,1) (R5 proof).
    float gx = floorf(fx), gy = floorf(fy), gz = floorf(fz);
    float wx = fx - gx, wy = fy - gy, wz = fz - gz;

    unsigned ux = (unsigned)(int)gx;
    unsigned uy = (unsigned)(int)gy;
    unsigned uz = (unsigned)(int)gz;

    unsigned hx0, hx1, hy0, hy1, hz0, hz1;
    if constexpr (POW2) {   // fold the *8 byte-scale into the hash components
        hx0 = ux << 3;        hx1 = hx0 + 8u;
        hy0 = uy * (P1 * 8u); hy1 = hy0 + (P1 * 8u);
        hz0 = uz * (P2 * 8u); hz1 = hz0 + (P2 * 8u);
    } else {
        hx0 = ux;       hx1 = ux + 1u;
        hy0 = uy * P1;  hy1 = hy0 + P1;
        hz0 = uz * P2;  hz1 = hz0 + P2;
    }
    unsigned h00 = hx0 ^ hy0, h01 = hx0 ^ hy1;
    unsigned h10 = hx1 ^ hy0, h11 = hx1 ^ hy1;

    auto fetch = [&](unsigned h) -> uint2 {
        unsigned addr;
        if constexpr (POW2) addr = h & (unsigned)((SIZE - 1) * 8);
        else                addr = (h % (unsigned)SIZE) * 8u;
        return *reinterpret_cast<const uint2*>(cb + addr);
    };

    // reference OFFSETS order: (i,j,k) for i in(0,1) j in(0,1) k in(0,1)
    r[0] = fetch(h00 ^ hz0);
    r[1] = fetch(h00 ^ hz1);
    r[2] = fetch(h01 ^ hz0);
    r[3] = fetch(h01 ^ hz1);
    r[4] = fetch(h10 ^ hz0);
    r[5] = fetch(h10 ^ hz1);
    r[6] = fetch(h11 ^ hz0);
    r[7] = fetch(h11 ^ hz1);

    float wx0 = 1.0f - wx, wy0 = 1.0f - wy, wz0 = 1.0f - wz;
    float w00 = wx0 * wy0, w01 = wx0 * wy, w10 = wx * wy0, w11 = wx * wy;
    w[0] = w00 * wz0; w[1] = w00 * wz;
    w[2] = w01 * wz0; w[3] = w01 * wz;
    w[4] = w10 * wz0; w[5] = w10 * wz;
    w[6] = w11 * wz0; w[7] = w11 * wz;
}

__device__ __forceinline__ void consume(const uint2 (&r)[8], const float (&w)[8],
                                        float& a0, float& a1, float& a2)
{
#pragma unroll
    for (int k = 0; k < 8; ++k)
        acc3(r[k], w[k], a0, a1, a2);
}

// Pre-kernel: pack codebooks 8,9 (f32x3) -> f16x4 into d_ws (runs every call).
__global__ void pack_kernel(const float* __restrict__ c8,
                            const float* __restrict__ c9,
                            __half2* __restrict__ ws)
{
    int t = blockIdx.x * blockDim.x + threadIdx.x;   // 0..2047
    const float* src = (t < 1024) ? (c8 + t * 3) : (c9 + (t - 1024) * 3);
    ws[t * 2 + 0] = __floats2half2_rn(src[0], src[1]);
    ws[t * 2 + 1] = __floats2half2_rn(src[2], 0.0f);
}

// 512-thr blocks, min 6 waves/EU -> VGPR cap ~85, 3 blocks/CU (24 waves/CU),
// 77 KB LDS of 160. Explicit 2-deep level pipeline supplies the MLP that
// extra waves no longer need to.
__global__ __launch_bounds__(512, 6)
void hashgrid_kernel(const float* __restrict__ pts,
                     const float* __restrict__ c0, const float* __restrict__ c1,
                     const float* __restrict__ c2, const float* __restrict__ c3,
                     const float* __restrict__ c4, const float* __restrict__ c5,
                     const float* __restrict__ c6, const float* __restrict__ c7,
                     const char* __restrict__ g8, const char* __restrict__ g9,
                     float* __restrict__ out, int npts, ResArr res)
{
    __shared__ __half cbh[LDS_ENTRIES * 4];   // 25656 B, levels 0..7

    {
        const float* srcs[8] = {c0, c1, c2, c3, c4, c5, c6, c7};
#pragma unroll
        for (int L = 0; L < 8; ++L) {
            for (int e = threadIdx.x; e < SIZES[L]; e += blockDim.x) {
                const float* s = srcs[L] + e * 3;
                __half2* d = reinterpret_cast<__half2*>(cbh + (ENTRY_OFS[L] + e) * 4);
                d[0] = __floats2half2_rn(s[0], s[1]);
                d[1] = __floats2half2_rn(s[2], 0.0f);
            }
        }
    }
    __syncthreads();

    const char* lds = reinterpret_cast<const char*>(cbh);

    const int S = gridDim.x * blockDim.x;
    for (int n = blockIdx.x * blockDim.x + threadIdx.x; n < npts; n += S) {
        // Nontemporal point loads: keep L1 free for the g8/g9 tables.
        float px = __builtin_nontemporal_load(pts + n * 3 + 0);
        float py = __builtin_nontemporal_load(pts + n * 3 + 1);
        float pz = __builtin_nontemporal_load(pts + n * 3 + 2);

        float a0 = 0.0f, a1 = 0.0f, a2 = 0.0f;

        uint2 rA[8], rB[8];
        float wA[8], wB[8];

        // Two-deep software pipeline over the 10 levels: issue level L+1's
        // 8 gathers before consuming level L's. In-order LDS/VMEM returns +
        // separate lgkm/vm counters keep 8-16 loads in flight per wave.
#define LD(L, SZ, GLB, BASE, R, W) \
        load_level<SZ, GLB>(BASE, res.r[L], px, py, pz, R, W);

        LD(0,   49, false, lds + ENTRY_OFS[0] * 8, rA, wA)
        LD(1,   64, false, lds + ENTRY_OFS[1] * 8, rB, wB)
        consume(rA, wA, a0, a1, a2);
        LD(2,  121, false, lds + ENTRY_OFS[2] * 8, rA, wA)
        consume(rB, wB, a0, a1, a2);
        LD(3,  196, false, lds + ENTRY_OFS[3] * 8, rB, wB)
        consume(rA, wA, a0, a1, a2);
        LD(4,  324, false, lds + ENTRY_OFS[4] * 8, rA, wA)
        consume(rB, wB, a0, a1, a2);
        LD(5,  529, false, lds + ENTRY_OFS[5] * 8, rB, wB)
        consume(rA, wA, a0, a1, a2);
        LD(6,  900, false, lds + ENTRY_OFS[6] * 8, rA, wA)
        consume(rB, wB, a0, a1, a2);
        LD(7, 1024, false, lds + ENTRY_OFS[7] * 8, rB, wB)
        consume(rA, wA, a0, a1, a2);
        LD(8, 1024, true,  g8,                     rA, wA)
        consume(rB, wB, a0, a1, a2);
        LD(9, 1024, true,  g9,                     rB, wB)
        consume(rA, wA, a0, a1, a2);
        consume(rB, wB, a0, a1, a2);
#undef LD

        __builtin_nontemporal_store(a0, out + n * 3 + 0);
        __builtin_nontemporal_store(a1, out + n * 3 + 1);
        __builtin_nontemporal_store(a2, out + n * 3 + 2);
    }
}

extern "C" void kernel_launch(void* const* d_in, const int* in_sizes, int n_in,
                              void* d_out, int out_size, void* d_ws, size_t ws_size,
                              hipStream_t stream)
{
    const float* pts = (const float*)d_in[0];
    const int npts = in_sizes[0] / 3;

    // Replicate numpy's exact double-precision LOD computation (glibc libm):
    // LOD 9 sits at 6*b^9 == 64.0 +/- ~1e-14, floor() is boundary-sensitive.
    ResArr ra;
    const double b = exp((log(64.0) - log(6.0)) / 9.0);
    for (int l = 0; l < NLOD; ++l)
        ra.r[l] = (int)(1.0 + floor(6.0 * pow(b, (double)l)));

    // Pack levels 8,9 into d_ws as f16x4 (8 KB each; rewritten every call).
    pack_kernel<<<dim3(8), dim3(256), 0, stream>>>(
        (const float*)d_in[9], (const float*)d_in[10], (__half2*)d_ws);

    const char* g8 = (const char*)d_ws;
    const char* g9 = (const char*)d_ws + 8192;

    // 768 blocks x 512 thr = 393216 threads (all resident at 3 blocks/CU),
    // ~5 grid-stride iterations.
    hashgrid_kernel<<<dim3(768), dim3(512), 0, stream>>>(
        pts,
        (const float*)d_in[1], (const float*)d_in[2], (const float*)d_in[3],
        (const float*)d_in[4], (const float*)d_in[5], (const float*)d_in[6],
        (const float*)d_in[7], (const float*)d_in[8],
        g8, g9,
        (float*)d_out, npts, ra);
}